// Round 8
// baseline (177.877 us; speedup 1.0000x reference)
//
#include <hip/hip_runtime.h>
#include <stdint.h>

typedef _Float16 f16;
typedef _Float16 f16x8 __attribute__((ext_vector_type(8)));
typedef _Float16 f16x4 __attribute__((ext_vector_type(4)));
typedef float f32x4 __attribute__((ext_vector_type(4)));

constexpr int EMB = 512;
constexpr int SEQ = 1024;
constexpr int NH = 8;
constexpr int DHEAD = 64;
constexpr int NTOK = 8192;  // B*S

#define GAS __attribute__((address_space(1)))
#define LAS __attribute__((address_space(3)))

#if __has_builtin(__builtin_amdgcn_exp2f)
#define EXP2F(x) __builtin_amdgcn_exp2f(x)
#else
#define EXP2F(x) exp2f(x)
#endif

static __device__ __forceinline__ void gload_lds16(const void* g, void* l) {
  __builtin_amdgcn_global_load_lds((const GAS void*)g, (LAS void*)l, 16, 0, 0);
}

// ---------------- weight / input packing ----------------

__global__ void k_pack_w(const float* __restrict__ Wq, const float* __restrict__ Wk,
                         const float* __restrict__ Wv, const float* __restrict__ Wo,
                         f16* __restrict__ wqkv, f16* __restrict__ wo) {
  int tid = blockIdx.x * 256 + threadIdx.x;
  if (tid < 2 * 1536 * 128) {  // qkv: [L][1536][512], 4 elems/thread
    int e4 = tid & 127;
    int f = (tid >> 7) % 1536;
    int l = tid / (128 * 1536);
    int part = f >> 9, fr = f & 511;
    const float* src = (part == 0 ? Wq : part == 1 ? Wk : Wv) + (size_t)l * EMB * EMB + (size_t)fr * EMB + e4 * 4;
    float4 v = *(const float4*)src;
    f16x4 hv = {(f16)v.x, (f16)v.y, (f16)v.z, (f16)v.w};
    *(f16x4*)(wqkv + ((size_t)l * 1536 + f) * EMB + e4 * 4) = hv;
  }
  if (tid < 2 * 512 * 128) {  // wo: [L][512][512]
    int e4 = tid & 127;
    int f = (tid >> 7) % 512;
    int l = tid / (128 * 512);
    float4 v = *(const float4*)(Wo + (size_t)l * EMB * EMB + (size_t)f * EMB + e4 * 4);
    f16x4 hv = {(f16)v.x, (f16)v.y, (f16)v.z, (f16)v.w};
    *(f16x4*)(wo + ((size_t)l * 512 + f) * EMB + e4 * 4) = hv;
  }
}

__global__ void k_pack_b(const float* __restrict__ bq, const float* __restrict__ bk,
                         const float* __restrict__ bv, float* __restrict__ bqkv) {
  int tid = blockIdx.x * 256 + threadIdx.x;
  if (tid < 2 * 1536) {
    int f = tid % 1536, l = tid / 1536;
    int part = f >> 9, fr = f & 511;
    bqkv[tid] = (part == 0 ? bq : part == 1 ? bk : bv)[l * EMB + fr];
  }
}

__global__ void k_cvt(const float* __restrict__ x, f16* __restrict__ out) {
  int i = (blockIdx.x * 256 + threadIdx.x) * 8;
  float4 a = *(const float4*)(x + i);
  float4 b = *(const float4*)(x + i + 4);
  f16x8 h = {(f16)a.x, (f16)a.y, (f16)a.z, (f16)a.w, (f16)b.x, (f16)b.y, (f16)b.z, (f16)b.w};
  *(f16x8*)(out + i) = h;
}

// adj -> f16 pre-scaled by 0.125*log2(e), packed in MFMA C-fragment order:
// adjP[((qrow*16 + tile)*16 + lanelow)*4 + n] = adj[qrow][tile*64 + n*16 + lanelow] * c
__global__ void k_pack_adjP(const float* __restrict__ adj, f16* __restrict__ adjP) {
  int tid = blockIdx.x * 256 + threadIdx.x;  // 262144 total
  int lo = tid & 15, t = (tid >> 4) & 15, qrow = tid >> 8;
  const float c = 0.125f * 1.44269504088896f;
  const float* row = adj + (size_t)qrow * SEQ + t * 64 + lo;
  f16x4 v = {(f16)(row[0] * c), (f16)(row[16] * c), (f16)(row[32] * c), (f16)(row[48] * c)};
  *(f16x4*)(adjP + (size_t)tid * 4) = v;
}

// ---------------- GEMM: C[M,N] = A[M,512] * Bw[N,512]^T + bias ----------------
// 2-phase double-buffered staging + XCD-chunked remap.
// BK=32 variant (MODE 1): 32KB LDS -> 3 blocks/CU co-resident (was 2 of 3).
// LDS layout: row-pair packed lines of 8 chunks: chunk(r,kc) = (r>>1)*8 +
// (r&1)*4 + (kc ^ ((r>>1)&3)) -> 2-way max bank pattern on b128 reads.
// BK=64 (MODE 0): original layout (grid 256 = 1 block/CU, fewer barriers wins).

template <int MODE, int BK>
__global__ __launch_bounds__(256) void k_gemm(const f16* __restrict__ A, const f16* __restrict__ Bw,
                                              const float* __restrict__ bias, float* __restrict__ Uout,
                                              f16* __restrict__ Qo, f16* __restrict__ Ko,
                                              f16* __restrict__ Vt) {
  constexpr int CH = 128 * BK / 8;  // f16x8 chunks per tile
  __shared__ f16x8 sA[2][CH];
  __shared__ f16x8 sB[2][CH];
  const int tid = threadIdx.x;
  const int lane = tid & 63;
  const int lanelow = lane & 15, lanehi = lane >> 4;
  const int wave = tid >> 6;
  const int wm = wave >> 1, wn = wave & 1;
  // XCD-chunked decode: low 6 bits -> m-tile (XCD-major), high bits -> n-tile
  const int flat = blockIdx.x;
  const int mt = (flat & 7) * 8 + ((flat >> 3) & 7);
  const int nt = flat >> 6;
  const int m0 = mt * 128, n0 = nt * 128;

  f32x4 acc[4][4] = {};

  const f16* aB = A + (size_t)m0 * EMB;
  const f16* bB = Bw + (size_t)n0 * EMB;

  // staging maps (linear LDS dest, inverse-swizzled global source)
  int srow[4], scl[4];
#pragma unroll
  for (int p = 0; p < (BK == 64 ? 4 : 2); ++p) {
    int c = p * 256 + tid;
    if (BK == 64) {
      srow[p] = c >> 3;
      scl[p] = (c & 7) ^ (srow[p] & 7);
    } else {
      int R = c >> 3, sub = c & 7;
      srow[p] = R * 2 + (sub >> 2);
      scl[p] = (sub & 3) ^ (R & 3);
    }
  }

#define GSTAGE(ktv, bufv)                                                                       \
  {                                                                                             \
    _Pragma("unroll") for (int p = 0; p < (BK == 64 ? 4 : 2); ++p) {                            \
      int c = p * 256 + tid;                                                                    \
      gload_lds16(aB + (size_t)srow[p] * EMB + (ktv) + scl[p] * 8, (char*)sA[bufv] + c * 16);   \
      gload_lds16(bB + (size_t)srow[p] * EMB + (ktv) + scl[p] * 8, (char*)sB[bufv] + c * 16);   \
    }                                                                                           \
  }

  GSTAGE(0, 0);
  __syncthreads();

  int cur = 0;
  for (int t = 0; t < EMB / BK; ++t) {
    if (t < EMB / BK - 1) GSTAGE((t + 1) * BK, cur ^ 1);
#pragma unroll
    for (int ks = 0; ks < BK / 32; ++ks) {
      f16x8 af[4], bf[4];
#pragma unroll
      for (int m = 0; m < 4; ++m) {
        int r = wm * 64 + m * 16 + lanelow;
        af[m] = (BK == 64) ? sA[cur][r * 8 + ((ks * 4 + lanehi) ^ (r & 7))]
                           : sA[cur][(r >> 1) * 8 + (r & 1) * 4 + (lanehi ^ ((r >> 1) & 3))];
      }
#pragma unroll
      for (int n = 0; n < 4; ++n) {
        int r = wn * 64 + n * 16 + lanelow;
        bf[n] = (BK == 64) ? sB[cur][r * 8 + ((ks * 4 + lanehi) ^ (r & 7))]
                           : sB[cur][(r >> 1) * 8 + (r & 1) * 4 + (lanehi ^ ((r >> 1) & 3))];
      }
      __builtin_amdgcn_s_setprio(1);
#pragma unroll
      for (int m = 0; m < 4; ++m)
#pragma unroll
        for (int n = 0; n < 4; ++n)
          acc[m][n] = __builtin_amdgcn_mfma_f32_16x16x32_f16(af[m], bf[n], acc[m][n], 0, 0, 0);
      __builtin_amdgcn_s_setprio(0);
    }
    __syncthreads();
    cur ^= 1;
  }
#undef GSTAGE

  // epilogue: C/D layout col = lane&15, row = (lane>>4)*4 + j
#pragma unroll
  for (int n = 0; n < 4; ++n) {
    int col = n0 + wn * 64 + n * 16 + lanelow;
    float bv = bias[col];
    if (MODE == 1 && (col >> 9) == 2) {
      // V-part: j -> s contiguous in Vt[bh][d][s]; pack 4 per store
      int fr = col & 511, hh = fr >> 6, d = fr & 63;
#pragma unroll
      for (int m = 0; m < 4; ++m) {
        int rbase = m0 + wm * 64 + m * 16 + lanehi * 4;
        int b = rbase >> 10, s = rbase & 1023;
        f16x4 pv = {(f16)(acc[m][n][0] + bv), (f16)(acc[m][n][1] + bv),
                    (f16)(acc[m][n][2] + bv), (f16)(acc[m][n][3] + bv)};
        *(f16x4*)(Vt + ((size_t)(b * NH + hh) * DHEAD + d) * SEQ + s) = pv;
      }
    } else {
#pragma unroll
      for (int m = 0; m < 4; ++m) {
        int rbase = m0 + wm * 64 + m * 16 + lanehi * 4;
#pragma unroll
        for (int j = 0; j < 4; ++j) {
          float v = acc[m][n][j] + bv;
          int row = rbase + j;
          if (MODE == 0) {
            Uout[(size_t)row * EMB + col] = v;
          } else {
            int part = col >> 9, fr = col & 511;
            int hh = fr >> 6, d = fr & 63;
            int b = row >> 10, s = row & 1023;
            int bh = b * NH + hh;
            if (part == 0)
              Qo[((size_t)bh * SEQ + s) * DHEAD + d] = (f16)v;
            else
              Ko[((size_t)bh * SEQ + s) * DHEAD + d] = (f16)v;
          }
        }
      }
    }
  }
}

// ---------------- flash attention ----------------
// R7: 16 q-rows/wave, KVBLK=64, 1024 blocks (64 bh x 16 qblk) -> 4096 waves.
// LDS 40KB -> 4 blocks/CU x 4 waves = 16 waves/CU (2x R6's TLP). K/V loads stay
// per-block LDS staging so halving rows/wave does NOT duplicate global traffic
// (the R1 failure mode). launch_bounds(256,4) caps VGPR at 128 (est ~110).

__global__ __launch_bounds__(256, 4) void k_attn(const f16* __restrict__ Q, const f16* __restrict__ K,
                                                 const f16* __restrict__ Vt, const f16* __restrict__ adjP,
                                                 f16* __restrict__ Ob) {
  __shared__ __align__(16) f16 sK[2][4096];   // [buf][64 rows x 8 chunks], swizzled (8KB each)
  __shared__ __align__(16) f16 sV[2][4096];
  __shared__ __align__(16) f16 Pl[4 * 1024];  // per-wave [16][64] P, swizzled (4KB)
  const int tid = threadIdx.x;
  const int lane = tid & 63;
  const int lanelow = lane & 15, lanehi = lane >> 4;
  const int wave = tid >> 6;
  f16* Plw = Pl + wave * 1024;

  // XCD-chunked decode (bijective on [0,1024)): XCD = flat&7 owns 8 bh, all 16 qblks
  const int flat = blockIdx.x;
  const int bh = (flat & 7) * 8 + ((flat >> 3) & 7);
  const int qblk = flat >> 6;  // [0,16)
  const int b = bh >> 3, hh = bh & 7;
  const int q0 = qblk * 64 + wave * 16;

  const f16* Kbase = K + (size_t)bh * SEQ * DHEAD;
  const f16* Vbase = Vt + (size_t)bh * DHEAD * SEQ;

  // staging: K 512 chunks + V 512 chunks of 16B per tile; 2 chunks each per thread
  const int c0 = tid, c1 = tid + 256;
  const int r0 = c0 >> 3, ch0 = (c0 & 7) ^ (r0 & 7);
  const int r1 = c1 >> 3, ch1 = (c1 & 7) ^ (r1 & 7);

#define STAGE(tv, bufv)                                                                   \
  {                                                                                       \
    const int kts = (tv)*64;                                                              \
    gload_lds16(Kbase + (size_t)(kts + r0) * DHEAD + ch0 * 8, (char*)sK[bufv] + c0 * 16); \
    gload_lds16(Kbase + (size_t)(kts + r1) * DHEAD + ch1 * 8, (char*)sK[bufv] + c1 * 16); \
    gload_lds16(Vbase + (size_t)r0 * SEQ + kts + ch0 * 8, (char*)sV[bufv] + c0 * 16);     \
    gload_lds16(Vbase + (size_t)r1 * SEQ + kts + ch1 * 8, (char*)sV[bufv] + c1 * 16);     \
  }

  // hoist Q fragments (16 rows)
  f16x8 qf[2];
#pragma unroll
  for (int ks = 0; ks < 2; ++ks)
    qf[ks] = *(const f16x8*)(Q + ((size_t)bh * SEQ + q0 + lanelow) * DHEAD + ks * 32 + lanehi * 8);

  // adj register prefetch (f16 C-frag packed): 4 x f16x4
  const f16* Ab = adjP + ((size_t)(q0 + lanehi * 4) * 256 + lanelow) * 4;
  f16x4 ab[4];
#define LOAD_A(tv)                                                           \
  {                                                                          \
    _Pragma("unroll") for (int j = 0; j < 4; ++j)                            \
        ab[j] = *(const f16x4*)(Ab + ((size_t)j * 256 + (tv)*16) * 4);       \
  }

  f32x4 oacc[4] = {};
  float lpart[4] = {};

  STAGE(0, 0);
  LOAD_A(0);
  __syncthreads();

  int cur = 0;
  for (int t = 0; t < 16; ++t) {
    if (t < 15) STAGE(t + 1, cur ^ 1);

    const f16* sKc = sK[cur];
    const f16* sVc = sV[cur];

    // --- QK^T from LDS K
    f32x4 sacc[4] = {};
#pragma unroll
    for (int ks = 0; ks < 2; ++ks) {
      f16x8 kf[4];
#pragma unroll
      for (int n = 0; n < 4; ++n) {
        int r = n * 16 + lanelow;
        kf[n] = *(const f16x8*)(sKc + (r * 8 + ((ks * 4 + lanehi) ^ (r & 7))) * 8);
      }
      __builtin_amdgcn_s_setprio(1);
#pragma unroll
      for (int n = 0; n < 4; ++n)
        sacc[n] = __builtin_amdgcn_mfma_f32_16x16x32_f16(qf[ks], kf[n], sacc[n], 0, 0, 0);
      __builtin_amdgcn_s_setprio(0);
    }

    // snapshot adj(t), prefetch adj(t+1)
    f16x4 acur[4];
#pragma unroll
    for (int j = 0; j < 4; ++j) acur[j] = ab[j];
    if (t < 15) LOAD_A(t + 1);

    // --- exp + PV interleaved by k-half: PV(ks=nh) only needs P cols n=2nh,2nh+1
#pragma unroll
    for (int nh = 0; nh < 2; ++nh) {
#pragma unroll
      for (int j = 0; j < 4; ++j) {
        const int prow = lanehi * 4 + j;
        const f16x4 a4 = acur[j];
#pragma unroll
        for (int nn = 0; nn < 2; ++nn) {
          const int n = nh * 2 + nn;
          float p = EXP2F(sacc[n][j] * (float)a4[n]);
          lpart[j] += p;
          Plw[prow * 64 + (((n * 2 + (lanelow >> 3)) ^ (prow & 7)) * 8) + (lanelow & 7)] = (f16)p;
        }
      }
      f16x8 pa, vf[4];
      pa = *(const f16x8*)(Plw + lanelow * 64 + (((nh * 4 + lanehi) ^ (lanelow & 7)) * 8));
#pragma unroll
      for (int n = 0; n < 4; ++n) {
        int r = n * 16 + lanelow;
        vf[n] = *(const f16x8*)(sVc + (r * 8 + ((nh * 4 + lanehi) ^ (r & 7))) * 8);
      }
      __builtin_amdgcn_s_setprio(1);
#pragma unroll
      for (int n = 0; n < 4; ++n)
        oacc[n] = __builtin_amdgcn_mfma_f32_16x16x32_f16(pa, vf[n], oacc[n], 0, 0, 0);
      __builtin_amdgcn_s_setprio(0);
    }

    __syncthreads();  // next buffer staged; all waves done with cur
    cur ^= 1;
  }
#undef STAGE
#undef LOAD_A

  // final: cross-lane reduce of row sums, normalize, write O to [B,S,E] f16
  float linv[4];
#pragma unroll
  for (int j = 0; j < 4; ++j) {
    float l = lpart[j];
#pragma unroll
    for (int off = 1; off < 16; off <<= 1) l += __shfl_xor(l, off, 16);
    linv[j] = 1.0f / l;
  }
#pragma unroll
  for (int n = 0; n < 4; ++n)
#pragma unroll
    for (int j = 0; j < 4; ++j) {
      int qrow = q0 + lanehi * 4 + j;
      float v = oacc[n][j] * linv[j];
      Ob[((size_t)b * SEQ + qrow) * EMB + hh * DHEAD + n * 16 + lanelow] = (f16)v;
    }
}

// ---------------- residual + layernorm (wave per row) ----------------

__global__ __launch_bounds__(256) void k_ln(const float* __restrict__ xin, const float* __restrict__ Uin,
                                            const float* __restrict__ gamma, const float* __restrict__ beta,
                                            float* __restrict__ xout, f16* __restrict__ xh_out) {
  const int row = blockIdx.x * 4 + (threadIdx.x >> 6);
  const int lane = threadIdx.x & 63;
  const size_t base = (size_t)row * EMB + lane * 8;
  float u[8];
  {
    float4 a0 = *(const float4*)(xin + base);
    float4 a1 = *(const float4*)(xin + base + 4);
    float4 c0 = *(const float4*)(Uin + base);
    float4 c1 = *(const float4*)(Uin + base + 4);
    u[0] = a0.x + c0.x; u[1] = a0.y + c0.y; u[2] = a0.z + c0.z; u[3] = a0.w + c0.w;
    u[4] = a1.x + c1.x; u[5] = a1.y + c1.y; u[6] = a1.z + c1.z; u[7] = a1.w + c1.w;
  }
  float s = 0.f;
#pragma unroll
  for (int i = 0; i < 8; ++i) s += u[i];
#pragma unroll
  for (int off = 1; off < 64; off <<= 1) s += __shfl_xor(s, off, 64);
  const float mu = s * (1.0f / EMB);
  float v = 0.f;
#pragma unroll
  for (int i = 0; i < 8; ++i) { float d = u[i] - mu; v += d * d; }
#pragma unroll
  for (int off = 1; off < 64; off <<= 1) v += __shfl_xor(v, off, 64);
  const float rs = rsqrtf(v * (1.0f / EMB) + 1e-5f);
  const int ci = lane * 8;
  float4 g0 = *(const float4*)(gamma + ci);
  float4 g1 = *(const float4*)(gamma + ci + 4);
  float4 b0 = *(const float4*)(beta + ci);
  float4 b1 = *(const float4*)(beta + ci + 4);
  float g[8] = {g0.x, g0.y, g0.z, g0.w, g1.x, g1.y, g1.z, g1.w};
  float be[8] = {b0.x, b0.y, b0.z, b0.w, b1.x, b1.y, b1.z, b1.w};
  float o[8];
#pragma unroll
  for (int i = 0; i < 8; ++i) o[i] = (u[i] - mu) * rs * g[i] + be[i];
  float4 o0 = {o[0], o[1], o[2], o[3]}, o1 = {o[4], o[5], o[6], o[7]};
  *(float4*)(xout + base) = o0;
  *(float4*)(xout + base + 4) = o1;
  if (xh_out) {
    f16x8 hv = {(f16)o[0], (f16)o[1], (f16)o[2], (f16)o[3], (f16)o[4], (f16)o[5], (f16)o[6], (f16)o[7]};
    *(f16x8*)(xh_out + base) = hv;
  }
}

// ---------------- launch ----------------

extern "C" void kernel_launch(void* const* d_in, const int* in_sizes, int n_in,
                              void* d_out, int out_size, void* d_ws, size_t ws_size,
                              hipStream_t stream) {
  (void)in_sizes; (void)n_in; (void)out_size; (void)ws_size;
  const float* x = (const float*)d_in[0];
  const float* adj = (const float*)d_in[1];
  const float* Wq = (const float*)d_in[2];
  const float* bq = (const float*)d_in[3];
  const float* Wk = (const float*)d_in[4];
  const float* bk = (const float*)d_in[5];
  const float* Wv = (const float*)d_in[6];
  const float* bv = (const float*)d_in[7];
  const float* Wo = (const float*)d_in[8];
  const float* bo = (const float*)d_in[9];
  const float* gamma = (const float*)d_in[10];
  const float* beta = (const float*)d_in[11];

  char* ws = (char*)d_ws;
  size_t off = 0;
  auto alloc = [&](size_t bytes) {
    char* p = ws + off;
    off += (bytes + 255) & ~(size_t)255;
    return p;
  };
  f16* wqkv = (f16*)alloc((size_t)2 * 1536 * 512 * sizeof(f16));
  f16* wo = (f16*)alloc((size_t)2 * 512 * 512 * sizeof(f16));
  float* bqkv = (float*)alloc((size_t)2 * 1536 * sizeof(float));
  f16* adjP = (f16*)alloc((size_t)SEQ * SEQ * sizeof(f16));
  f16* xh = (f16*)alloc((size_t)NTOK * EMB * sizeof(f16));
  f16* Qb = (f16*)alloc((size_t)NTOK * EMB * sizeof(f16));
  f16* Kb = (f16*)alloc((size_t)NTOK * EMB * sizeof(f16));
  f16* Vtb = (f16*)alloc((size_t)NTOK * EMB * sizeof(f16));
  f16* Ob = (f16*)alloc((size_t)NTOK * EMB * sizeof(f16));
  float* U = (float*)alloc((size_t)NTOK * EMB * sizeof(float));
  float* x1 = (float*)alloc((size_t)NTOK * EMB * sizeof(float));

  k_pack_w<<<1536, 256, 0, stream>>>(Wq, Wk, Wv, Wo, wqkv, wo);
  k_pack_b<<<12, 256, 0, stream>>>(bq, bk, bv, bqkv);
  k_pack_adjP<<<1024, 256, 0, stream>>>(adj, adjP);
  k_cvt<<<2048, 256, 0, stream>>>(x, xh);

  const float* xcur = x;
  for (int l = 0; l < 2; ++l) {
    k_gemm<1, 32><<<768, 256, 0, stream>>>(xh, wqkv + (size_t)l * 1536 * 512, bqkv + l * 1536,
                                           nullptr, Qb, Kb, Vtb);
    k_attn<<<1024, 256, 0, stream>>>(Qb, Kb, Vtb, adjP, Ob);
    k_gemm<0, 64><<<256, 256, 0, stream>>>(Ob, wo + (size_t)l * 512 * 512, bo + l * 512,
                                           U, nullptr, nullptr, nullptr);
    float* xnext = (l == 0) ? x1 : (float*)d_out;
    k_ln<<<2048, 256, 0, stream>>>(xcur, U, gamma + l * 512, beta + l * 512, xnext,
                                   (l == 0) ? xh : nullptr);
    xcur = xnext;
  }
}